// Round 4
// baseline (120.815 us; speedup 1.0000x reference)
//
#include <hip/hip_runtime.h>

typedef unsigned short u16;
typedef unsigned int u32;
typedef __attribute__((ext_vector_type(8))) short bf16x8;
typedef __attribute__((ext_vector_type(4))) float f32x4;

#define NUM_OPS 8
#define M_DIM 4096   // B*T
#define K_DIM 1024
#define N_DIM 1024
#define BK 32
#define KITERS (K_DIM / BK)
#define PITCH 40     // sA row pitch (u16): bank-stride 20 -> 2-way (free) frag reads

// ---- helpers ----------------------------------------------------------

__device__ __forceinline__ u16 f2b(float f) {
  union { float f; u32 u; } v; v.f = f;
  u32 r = v.u + 0x7fffu + ((v.u >> 16) & 1u);  // RNE
  return (u16)(r >> 16);
}

// pack two f32 -> (bf16(b)<<16)|bf16(a), round-half-up
__device__ __forceinline__ u32 pk2(float a, float b) {
  u32 ua = __float_as_uint(a) + 0x8000u;
  u32 ub = __float_as_uint(b) + 0x8000u;
  return (ua >> 16) | (ub & 0xffff0000u);
}

__device__ __forceinline__ int compute_idx(const float* __restrict__ logits,
                                           const float* __restrict__ u) {
  int best = 0; float bv = -3.4e38f;
#pragma unroll
  for (int i = 0; i < NUM_OPS; ++i) {
    float v = logits[i] - logf(-logf(u[i]));  // logits + gumbel
    if (v > bv) { bv = v; best = i; }
  }
  return best;
}

// async global->LDS, 16B/lane; LDS dest = wave-uniform base + lane*16
__device__ __forceinline__ void gld_lds16(const void* g, void* l) {
  __builtin_amdgcn_global_load_lds(
      (__attribute__((address_space(1))) void*)(g),
      (__attribute__((address_space(3))) void*)(unsigned)(unsigned long long)(l),
      16, 0, 0);
}

// ---- prep: W[idx] -> wt bf16, [n][k] layout (transpose) ----------------
// 256 blocks x 256 thr, one 64x64 tile each. ~6.3 MB traffic.
__global__ void prep_kernel(const float* __restrict__ W,
                            const float* __restrict__ logits,
                            const float* __restrict__ u,
                            u16* __restrict__ wt) {
  __shared__ u16 t[64][66];  // +2 pad
  const int tid = threadIdx.x, wb = blockIdx.x;
  const int kt = wb >> 4, nt = wb & 15;
  const int idx = compute_idx(logits, u);
  const float* Wi = W + (size_t)idx * K_DIM * N_DIM;
#pragma unroll
  for (int it = 0; it < 16; ++it) {
    int i = it * 256 + tid;
    int r = i >> 6, c = i & 63;
    t[r][c] = f2b(Wi[(size_t)(kt * 64 + r) * N_DIM + nt * 64 + c]);
  }
  __syncthreads();
#pragma unroll
  for (int it = 0; it < 8; ++it) {  // u32 = two k per write, coalesced along k
    int i = it * 256 + tid;
    int n = i >> 5, kp = i & 31;
    u32 lo = t[2 * kp][n], hi = t[2 * kp + 1][n];
    *(u32*)(wt + (size_t)(nt * 64 + n) * K_DIM + kt * 64 + 2 * kp) =
        lo | (hi << 16);
  }
}

// ---- GEMM: out = x * wt^T + b[idx] ------------------------------------
// BM=128, BN=64, BK=32; 256 thr = 4 waves (2m x 2n), wave tile 64x32.
// Grid 512 = 2 blocks/CU (independent barrier groups).
// A: reg-prefetched float4 from fp32 x, packed bf16 -> padded sA.
// B: global_load_lds 16B from bf16 wt -> unpadded sB with source XOR swizzle.
// Double-buffered, ONE barrier/iter; loads for k+1 issued right after it.
__global__ __launch_bounds__(256) void gemm_kernel(
    const float* __restrict__ x, const u16* __restrict__ wt,
    const float* __restrict__ bvec, const float* __restrict__ logits,
    const float* __restrict__ u, float* __restrict__ out) {
  __shared__ u16 sA[2][128 * PITCH];  // 10 KB each
  __shared__ u16 sB[2][64 * 32];      // 4 KB each

  const int tid = threadIdx.x;
  const int w = tid >> 6, L = tid & 63;
  const int m0 = blockIdx.y * 128;
  const int n0 = blockIdx.x * 64;

  // A staging: thread t -> row t>>1, k-half t&1 (16 contiguous floats)
  const int arow = tid >> 1, akh = tid & 1;
  const float* gA = x + (size_t)(m0 + arow) * K_DIM + akh * 16;
  const int lA = arow * PITCH + akh * 16;  // u16 units, 16B-aligned

  // B staging: wave w -> rows 16w..16w+15; source k-quad XOR swizzle
  const int brow = 16 * w + (L >> 2);
  const int kqs = (L & 3) ^ (((L >> 2) & 3) ^ (L >> 4));  // (L&3)^sw(brow)
  const u16* gB = wt + (size_t)(n0 + brow) * K_DIM + kqs * 8;
  const int lB = w * 512 + L * 8;  // wave-uniform base + L*16B

  // fragment offsets
  const int wm = w & 1, wn = w >> 1;
  const int swf = (L & 3) ^ ((L >> 2) & 3);  // sw(r) for r = ...+(L&15)
  int aoff[4], boff[2];
#pragma unroll
  for (int mt = 0; mt < 4; ++mt)
    aoff[mt] = (64 * wm + 16 * mt + (L & 15)) * PITCH + (L >> 4) * 8;
#pragma unroll
  for (int nt = 0; nt < 2; ++nt)
    boff[nt] = (32 * wn + 16 * nt + (L & 15)) * 32 + ((L >> 4) ^ swf) * 8;

  f32x4 acc[4][2] = {};

  // prologue: k-block 0
  gld_lds16(gB, &sB[0][lB]);
  float4 ra[4];
#pragma unroll
  for (int i = 0; i < 4; ++i) ra[i] = *(const float4*)(gA + i * 4);

  for (int kk = 0; kk < KITERS; ++kk) {
    const int cur = kk & 1, nxt = cur ^ 1;

    // pack A regs -> sA[cur] (two b128 writes)
    uint4 p0, p1;
    p0.x = pk2(ra[0].x, ra[0].y); p0.y = pk2(ra[0].z, ra[0].w);
    p0.z = pk2(ra[1].x, ra[1].y); p0.w = pk2(ra[1].z, ra[1].w);
    p1.x = pk2(ra[2].x, ra[2].y); p1.y = pk2(ra[2].z, ra[2].w);
    p1.z = pk2(ra[3].x, ra[3].y); p1.w = pk2(ra[3].z, ra[3].w);
    *(uint4*)(&sA[cur][lA]) = p0;
    *(uint4*)(&sA[cur][lA + 8]) = p1;

    __syncthreads();  // drains vmcnt: B(kk) landed (issued last iter); A writes visible

    if (kk + 1 < KITERS) {  // issue k+1 now; full iter of cover before next barrier
      gld_lds16(gB + (kk + 1) * BK, &sB[nxt][lB]);
      const float* gA2 = gA + (kk + 1) * BK;
#pragma unroll
      for (int i = 0; i < 4; ++i) ra[i] = *(const float4*)(gA2 + i * 4);
    }

    bf16x8 af[4], bf[2];
#pragma unroll
    for (int mt = 0; mt < 4; ++mt) af[mt] = *(const bf16x8*)(&sA[cur][aoff[mt]]);
#pragma unroll
    for (int nt = 0; nt < 2; ++nt) bf[nt] = *(const bf16x8*)(&sB[cur][boff[nt]]);
#pragma unroll
    for (int mt = 0; mt < 4; ++mt)
#pragma unroll
      for (int nt = 0; nt < 2; ++nt)
        acc[mt][nt] = __builtin_amdgcn_mfma_f32_16x16x32_bf16(
            af[mt], bf[nt], acc[mt][nt], 0, 0, 0);
    // no trailing barrier: buf[nxt] writers (next iter) are gated by this
    // iter's barrier; buf[nxt] readers all passed it too
  }

  // epilogue: C/D layout col=lane&15, row=(lane>>4)*4+reg
  const int idx = compute_idx(logits, u);
  const float* bi = bvec + (size_t)idx * N_DIM;
#pragma unroll
  for (int mt = 0; mt < 4; ++mt) {
    int row = m0 + 64 * wm + 16 * mt + (L >> 4) * 4;
#pragma unroll
    for (int nt = 0; nt < 2; ++nt) {
      int col = n0 + 32 * wn + 16 * nt + (L & 15);
      float bv = bi[col];
#pragma unroll
      for (int r = 0; r < 4; ++r)
        out[(size_t)(row + r) * N_DIM + col] = acc[mt][nt][r] + bv;
    }
  }
}

// ---- launch -----------------------------------------------------------

extern "C" void kernel_launch(void* const* d_in, const int* in_sizes, int n_in,
                              void* d_out, int out_size, void* d_ws, size_t ws_size,
                              hipStream_t stream) {
  const float* x      = (const float*)d_in[0];
  const float* W      = (const float*)d_in[1];
  const float* bvec   = (const float*)d_in[2];
  const float* logits = (const float*)d_in[3];
  const float* u      = (const float*)d_in[4];
  float* out = (float*)d_out;

  u16* wt = (u16*)d_ws;  // 1024*1024 bf16 = 2 MB, [n][k]

  prep_kernel<<<256, 256, 0, stream>>>(W, logits, u, wt);
  dim3 grid(N_DIM / 64, M_DIM / 128);  // 16 x 32 = 512 blocks = 2/CU
  gemm_kernel<<<grid, 256, 0, stream>>>(x, wt, bvec, logits, u, out);
}

// Round 5
// 112.226 us; speedup vs baseline: 1.0765x; 1.0765x over previous
//
#include <hip/hip_runtime.h>

typedef unsigned short u16;
typedef unsigned int u32;
typedef __attribute__((ext_vector_type(8))) short bf16x8;
typedef __attribute__((ext_vector_type(4))) float f32x4;

#define NUM_OPS 8
#define M_DIM 4096   // B*T
#define K_DIM 1024
#define N_DIM 1024
#define BK 32
#define KITERS (K_DIM / BK)   // 32 k-tiles
// Fragment-tiled layouts: operand stored as 1KB chunks, chunk = 16 rows x 32 k,
// slot l (16B) = rows (l&15), k = (l>>4)*8 + j  == MFMA A/B fragment lane order.
// chunk index = rowtile * 32 + ktile.

// ---- helpers ----------------------------------------------------------

__device__ __forceinline__ u16 f2b(float f) {
  union { float f; u32 u; } v; v.f = f;
  u32 r = v.u + 0x7fffu + ((v.u >> 16) & 1u);  // RNE
  return (u16)(r >> 16);
}

__device__ __forceinline__ u32 pk2(float a, float b) {  // bf16(a) | bf16(b)<<16
  return (u32)f2b(a) | ((u32)f2b(b) << 16);
}

__device__ __forceinline__ int compute_idx(const float* __restrict__ logits,
                                           const float* __restrict__ u) {
  int best = 0; float bv = -3.4e38f;
#pragma unroll
  for (int i = 0; i < NUM_OPS; ++i) {
    float v = logits[i] - logf(-logf(u[i]));  // logits + gumbel
    if (v > bv) { bv = v; best = i; }
  }
  return best;
}

// async global->LDS, 16B/lane
__device__ __forceinline__ void gld_lds16(const void* g, void* l) {
  __builtin_amdgcn_global_load_lds(
      (__attribute__((address_space(1))) void*)(g),
      (__attribute__((address_space(3))) void*)(unsigned)(unsigned long long)(l),
      16, 0, 0);
}

// ---- prep: x -> xb (frag-tiled bf16), W[idx] -> wt (frag-tiled bf16, B-op) ----
// bid < 2048: x part. thread -> one 16B slot. chunk = bid*4 + (tid>>6).
// bid >= 2048: W transpose part, 64x64 tile per block via LDS.
__global__ void prep_kernel(const float* __restrict__ x, const float* __restrict__ W,
                            const float* __restrict__ logits, const float* __restrict__ u,
                            u16* __restrict__ xb, u16* __restrict__ wt) {
  const int tid = threadIdx.x;
  const int bid = blockIdx.x;
  if (bid < 2048) {
    const int chunk = bid * 4 + (tid >> 6), l = tid & 63;
    const int mtile = chunk >> 5, ktile = chunk & 31;
    const float* src = x + (size_t)(mtile * 16 + (l & 15)) * K_DIM
                         + ktile * 32 + (l >> 4) * 8;
    float4 f0 = *(const float4*)(src);
    float4 f1 = *(const float4*)(src + 4);
    uint4 p;
    p.x = pk2(f0.x, f0.y); p.y = pk2(f0.z, f0.w);
    p.z = pk2(f1.x, f1.y); p.w = pk2(f1.z, f1.w);
    *(uint4*)(xb + (size_t)chunk * 512 + l * 8) = p;
  } else {
    __shared__ u16 t[64][66];  // [k][n], +2 pad
    const int wb = bid - 2048;
    const int kt = wb >> 4, nt = wb & 15;   // 64x64 tile of W[k][n]
    const int idx = compute_idx(logits, u);
    const float* Wi = W + (size_t)idx * K_DIM * N_DIM;
#pragma unroll
    for (int it = 0; it < 16; ++it) {
      int i = it * 256 + tid;
      int r = i >> 6, c = i & 63;
      t[r][c] = f2b(Wi[(size_t)(kt * 64 + r) * N_DIM + nt * 64 + c]);
    }
    __syncthreads();
    // write 8 chunks (4 ntiles x 2 ktiles), frag order: slot l -> n=(l&15), k=(l>>4)*8+j
#pragma unroll
    for (int it = 0; it < 2; ++it) {
      int s = it * 256 + tid;
      int c = s >> 6, l = s & 63;
      int ntl = c & 3, ktl = c >> 2;
      int kb = ktl * 32 + (l >> 4) * 8, nn = ntl * 16 + (l & 15);
      uint4 p;
      p.x = (u32)t[kb + 0][nn] | ((u32)t[kb + 1][nn] << 16);
      p.y = (u32)t[kb + 2][nn] | ((u32)t[kb + 3][nn] << 16);
      p.z = (u32)t[kb + 4][nn] | ((u32)t[kb + 5][nn] << 16);
      p.w = (u32)t[kb + 6][nn] | ((u32)t[kb + 7][nn] << 16);
      int chunk = (nt * 4 + ntl) * 32 + (kt * 2 + ktl);
      *(uint4*)(wt + (size_t)chunk * 512 + l * 8) = p;
    }
  }
}

// ---- GEMM: out = x * W[idx] + b[idx], frag-tiled operands --------------
// BM=128, BN=128, BK=32; 256 thr = 4 waves (2m x 2n), wave tile 64x64.
// Grid 256, XCD-swizzled so each XCD's 32 blocks share 4 m-slabs (1MB xb)
// + wt (2MB) -> L2-resident reuse. Staging = 4 gld_lds16/wave; frag reads
// = 8 ds_read_b128/wave at base+L*16 (bank-conflict-free). Double-buffered.
__global__ __launch_bounds__(256) void gemm_kernel(
    const u16* __restrict__ xb, const u16* __restrict__ wt,
    const float* __restrict__ bvec, const float* __restrict__ logits,
    const float* __restrict__ u, float* __restrict__ out) {
  __shared__ u16 sA[2][8 * 512];  // 8 chunks (128 rows x 32 k) per buf, 8KB
  __shared__ u16 sB[2][8 * 512];

  const int tid = threadIdx.x;
  const int w = tid >> 6, L = tid & 63;
  const int bid = blockIdx.x;
  const int mb = (bid & 7) * 4 + (bid >> 6);  // XCD swizzle: bid%8 groups share mb range
  const int nb = (bid >> 3) & 7;
  const int m0 = mb * 128, n0 = nb * 128;

  // staging: wave w stages A chunks {2w,2w+1} and B chunks {2w,2w+1} of the tile
  const int c0 = 2 * w, c1 = 2 * w + 1;
  const u16* gA0 = xb + ((size_t)((mb * 8 + c0) * 32)) * 512 + L * 8;
  const u16* gA1 = xb + ((size_t)((mb * 8 + c1) * 32)) * 512 + L * 8;
  const u16* gB0 = wt + ((size_t)((nb * 8 + c0) * 32)) * 512 + L * 8;
  const u16* gB1 = wt + ((size_t)((nb * 8 + c1) * 32)) * 512 + L * 8;
  const int lA0 = c0 * 512 + L * 8, lA1 = c1 * 512 + L * 8;  // u16 units

  const int wm = w & 1, wn = w >> 1;
  // frag read offsets: local chunk (4*half + t), sequential lanes
  int aoff[4], boff[4];
#pragma unroll
  for (int t = 0; t < 4; ++t) {
    aoff[t] = (4 * wm + t) * 512 + L * 8;
    boff[t] = (4 * wn + t) * 512 + L * 8;
  }

  f32x4 acc[4][4] = {};

  // prologue: stage k-tile 0 into buf 0
  gld_lds16(gA0, &sA[0][lA0]);
  gld_lds16(gA1, &sA[0][lA1]);
  gld_lds16(gB0, &sB[0][lA0]);
  gld_lds16(gB1, &sB[0][lA1]);

  for (int kk = 0; kk < KITERS; ++kk) {
    const int cur = kk & 1, nxt = cur ^ 1;
    __syncthreads();  // vmcnt(0) drain: buf[cur] staged; prior reads of buf[nxt] done

    if (kk + 1 < KITERS) {  // stage k+1 into buf[nxt]; full iter of cover
      const int ko = (kk + 1) * 512;
      gld_lds16(gA0 + ko, &sA[nxt][lA0]);
      gld_lds16(gA1 + ko, &sA[nxt][lA1]);
      gld_lds16(gB0 + ko, &sB[nxt][lA0]);
      gld_lds16(gB1 + ko, &sB[nxt][lA1]);
    }

    bf16x8 af[4], bf[4];
#pragma unroll
    for (int t = 0; t < 4; ++t) {
      af[t] = *(const bf16x8*)(&sA[cur][aoff[t]]);
      bf[t] = *(const bf16x8*)(&sB[cur][boff[t]]);
    }
#pragma unroll
    for (int mt = 0; mt < 4; ++mt)
#pragma unroll
      for (int nt = 0; nt < 4; ++nt)
        acc[mt][nt] = __builtin_amdgcn_mfma_f32_16x16x32_bf16(
            af[mt], bf[nt], acc[mt][nt], 0, 0, 0);
  }

  // epilogue: C/D layout col=lane&15, row=(lane>>4)*4+reg
  const int idx = compute_idx(logits, u);
  const float* bi = bvec + (size_t)idx * N_DIM;
#pragma unroll
  for (int mt = 0; mt < 4; ++mt) {
    int row = m0 + 64 * wm + 16 * mt + (L >> 4) * 4;
#pragma unroll
    for (int nt = 0; nt < 4; ++nt) {
      int col = n0 + 64 * wn + 16 * nt + (L & 15);
      float bv = bi[col];
#pragma unroll
      for (int r = 0; r < 4; ++r)
        out[(size_t)(row + r) * N_DIM + col] = acc[mt][nt][r] + bv;
    }
  }
}

// ---- launch -----------------------------------------------------------

extern "C" void kernel_launch(void* const* d_in, const int* in_sizes, int n_in,
                              void* d_out, int out_size, void* d_ws, size_t ws_size,
                              hipStream_t stream) {
  const float* x      = (const float*)d_in[0];
  const float* W      = (const float*)d_in[1];
  const float* bvec   = (const float*)d_in[2];
  const float* logits = (const float*)d_in[3];
  const float* u      = (const float*)d_in[4];
  float* out = (float*)d_out;

  u16* xb = (u16*)d_ws;                          // frag-tiled x, 8 MB
  u16* wt = (u16*)d_ws + (size_t)M_DIM * K_DIM;  // frag-tiled W[idx]^T, 2 MB

  prep_kernel<<<2048 + 256, 256, 0, stream>>>(x, W, logits, u, xb, wt);
  gemm_kernel<<<256, 256, 0, stream>>>(xb, wt, bvec, logits, u, out);
}

// Round 6
// 104.283 us; speedup vs baseline: 1.1585x; 1.0762x over previous
//
#include <hip/hip_runtime.h>

typedef unsigned short u16;
typedef unsigned int u32;
typedef __attribute__((ext_vector_type(8))) short bf16x8;
typedef __attribute__((ext_vector_type(4))) float f32x4;

#define NUM_OPS 8
#define M_DIM 4096   // B*T
#define K_DIM 1024
#define N_DIM 1024
#define BK 64
#define KITERS (K_DIM / BK)   // 16
// Fragment-tiled operands: 1KB chunks = 16 rows x 32 k; slot l (16B) holds
// rows (l&15), k=(l>>4)*8+j  == exact MFMA A/B fragment lane order.
// chunk index = rowtile*32 + ktile (ktile of 32).

// ---- helpers ----------------------------------------------------------

__device__ __forceinline__ u16 f2b(float f) {
  union { float f; u32 u; } v; v.f = f;
  u32 r = v.u + 0x7fffu + ((v.u >> 16) & 1u);  // RNE
  return (u16)(r >> 16);
}

__device__ __forceinline__ u32 pk2(float a, float b) {  // bf16(a) | bf16(b)<<16
  return (u32)f2b(a) | ((u32)f2b(b) << 16);
}

__device__ __forceinline__ int compute_idx(const float* __restrict__ logits,
                                           const float* __restrict__ u) {
  int best = 0; float bv = -3.4e38f;
#pragma unroll
  for (int i = 0; i < NUM_OPS; ++i) {
    float v = logits[i] - logf(-logf(u[i]));  // logits + gumbel
    if (v > bv) { bv = v; best = i; }
  }
  return best;
}

// async global->LDS, 16B/lane
__device__ __forceinline__ void gld_lds16(const void* g, void* l) {
  __builtin_amdgcn_global_load_lds(
      (__attribute__((address_space(1))) void*)(g),
      (__attribute__((address_space(3))) void*)(unsigned)(unsigned long long)(l),
      16, 0, 0);
}

// ---- prep: x -> xb (frag-tiled bf16), W[idx] -> wt (frag-tiled bf16) ----
__global__ void prep_kernel(const float* __restrict__ x, const float* __restrict__ W,
                            const float* __restrict__ logits, const float* __restrict__ u,
                            u16* __restrict__ xb, u16* __restrict__ wt) {
  const int tid = threadIdx.x;
  const int bid = blockIdx.x;
  if (bid < 2048) {
    const int chunk = bid * 4 + (tid >> 6), l = tid & 63;
    const int mtile = chunk >> 5, ktile = chunk & 31;
    const float* src = x + (size_t)(mtile * 16 + (l & 15)) * K_DIM
                         + ktile * 32 + (l >> 4) * 8;
    float4 f0 = *(const float4*)(src);
    float4 f1 = *(const float4*)(src + 4);
    uint4 p;
    p.x = pk2(f0.x, f0.y); p.y = pk2(f0.z, f0.w);
    p.z = pk2(f1.x, f1.y); p.w = pk2(f1.z, f1.w);
    *(uint4*)(xb + (size_t)chunk * 512 + l * 8) = p;
  } else {
    __shared__ u16 t[64][66];  // [k][n], +2 pad
    const int wb = bid - 2048;
    const int kt = wb >> 4, nt = wb & 15;   // 64x64 tile of W[k][n]
    const int idx = compute_idx(logits, u);
    const float* Wi = W + (size_t)idx * K_DIM * N_DIM;
#pragma unroll
    for (int it = 0; it < 16; ++it) {
      int i = it * 256 + tid;
      int r = i >> 6, c = i & 63;
      t[r][c] = f2b(Wi[(size_t)(kt * 64 + r) * N_DIM + nt * 64 + c]);
    }
    __syncthreads();
#pragma unroll
    for (int it = 0; it < 2; ++it) {
      int s = it * 256 + tid;
      int c = s >> 6, l = s & 63;
      int ntl = c & 3, ktl = c >> 2;
      int kb = ktl * 32 + (l >> 4) * 8, nn = ntl * 16 + (l & 15);
      uint4 p;
      p.x = (u32)t[kb + 0][nn] | ((u32)t[kb + 1][nn] << 16);
      p.y = (u32)t[kb + 2][nn] | ((u32)t[kb + 3][nn] << 16);
      p.z = (u32)t[kb + 4][nn] | ((u32)t[kb + 5][nn] << 16);
      p.w = (u32)t[kb + 6][nn] | ((u32)t[kb + 7][nn] << 16);
      int chunk = (nt * 4 + ntl) * 32 + (kt * 2 + ktl);
      *(uint4*)(wt + (size_t)chunk * 512 + l * 8) = p;
    }
  }
}

// ---- GEMM: out = x * W[idx] + b[idx] -----------------------------------
// BM=64, BN=128, BK=64; 256 thr = 4 waves (2m x 2n), wave tile 32x64.
// Grid 512 = 2 blocks/CU: two INDEPENDENT barrier groups per CU -> 2
// waves/SIMD interleave (one computes while the other drains/stages).
// 24 chunks/iter staged via gld_lds16 (6/wave), dbuf, one barrier/iter.
__global__ __launch_bounds__(256) void gemm_kernel(
    const u16* __restrict__ xb, const u16* __restrict__ wt,
    const float* __restrict__ bvec, const float* __restrict__ logits,
    const float* __restrict__ u, float* __restrict__ out) {
  // unified chunk store: A chunks 0..7, B chunks 8..23 (24 KB per buf)
  __shared__ u16 sm[2][24 * 512];

  const int tid = threadIdx.x;
  const int w = tid >> 6, L = tid & 63;
  const int bid = blockIdx.x;
  const int mb = (bid & 7) * 8 + (bid >> 6);   // [0,64): XCD-local m-slabs
  const int nb = (bid >> 3) & 7;               // [0,8)

  // staging: wave w handles items 6w..6w+5; item<8 -> A chunk, else B
  const u16* gsrc[6];
  int lofs[6];
#pragma unroll
  for (int j = 0; j < 6; ++j) {
    int item = 6 * w + j;
    if (item < 8) {
      int mt = item >> 1, dk = item & 1;
      gsrc[j] = xb + ((size_t)((mb * 4 + mt) * 32 + dk)) * 512 + L * 8;
    } else {
      int t = item - 8, nt = t >> 1, dk = t & 1;
      gsrc[j] = wt + ((size_t)((nb * 8 + nt) * 32 + dk)) * 512 + L * 8;
    }
    lofs[j] = item * 512 + L * 8;
  }

  const int wm = w & 1, wn = w >> 1;
  int aoff[2][2], boff[4][2];
#pragma unroll
  for (int f = 0; f < 2; ++f)
#pragma unroll
    for (int dk = 0; dk < 2; ++dk)
      aoff[f][dk] = ((2 * wm + f) * 2 + dk) * 512 + L * 8;
#pragma unroll
  for (int t = 0; t < 4; ++t)
#pragma unroll
    for (int dk = 0; dk < 2; ++dk)
      boff[t][dk] = (8 + (4 * wn + t) * 2 + dk) * 512 + L * 8;

  f32x4 acc[2][4] = {};

  // prologue: stage k-iter 0 into buf 0
#pragma unroll
  for (int j = 0; j < 6; ++j) gld_lds16(gsrc[j], &sm[0][lofs[j]]);

  for (int kk = 0; kk < KITERS; ++kk) {
    const int cur = kk & 1, nxt = cur ^ 1;
    __syncthreads();  // drains own staging (vmcnt); all waves' chunks landed

    if (kk + 1 < KITERS) {
      const int ko = (kk + 1) * 1024;  // 2 ktiles per iter, 512 u16 each
#pragma unroll
      for (int j = 0; j < 6; ++j) gld_lds16(gsrc[j] + ko, &sm[nxt][lofs[j]]);
    }

    bf16x8 af[2][2], bf[4][2];
#pragma unroll
    for (int f = 0; f < 2; ++f)
#pragma unroll
      for (int dk = 0; dk < 2; ++dk)
        af[f][dk] = *(const bf16x8*)(&sm[cur][aoff[f][dk]]);
#pragma unroll
    for (int t = 0; t < 4; ++t)
#pragma unroll
      for (int dk = 0; dk < 2; ++dk)
        bf[t][dk] = *(const bf16x8*)(&sm[cur][boff[t][dk]]);
#pragma unroll
    for (int dk = 0; dk < 2; ++dk)
#pragma unroll
      for (int f = 0; f < 2; ++f)
#pragma unroll
        for (int t = 0; t < 4; ++t)
          acc[f][t] = __builtin_amdgcn_mfma_f32_16x16x32_bf16(
              af[f][dk], bf[t][dk], acc[f][t], 0, 0, 0);
    // no trailing barrier: buf[nxt] writers are gated by this iter's barrier
  }

  // epilogue: C/D layout col=lane&15, row=(lane>>4)*4+reg
  const int idx = compute_idx(logits, u);
  const float* bi = bvec + (size_t)idx * N_DIM;
#pragma unroll
  for (int f = 0; f < 2; ++f) {
    int row = mb * 64 + 32 * wm + 16 * f + (L >> 4) * 4;
#pragma unroll
    for (int t = 0; t < 4; ++t) {
      int col = nb * 128 + 64 * wn + 16 * t + (L & 15);
      float bv = bi[col];
#pragma unroll
      for (int r = 0; r < 4; ++r)
        out[(size_t)(row + r) * N_DIM + col] = acc[f][t][r] + bv;
    }
  }
}

// ---- launch -----------------------------------------------------------

extern "C" void kernel_launch(void* const* d_in, const int* in_sizes, int n_in,
                              void* d_out, int out_size, void* d_ws, size_t ws_size,
                              hipStream_t stream) {
  const float* x      = (const float*)d_in[0];
  const float* W      = (const float*)d_in[1];
  const float* bvec   = (const float*)d_in[2];
  const float* logits = (const float*)d_in[3];
  const float* u      = (const float*)d_in[4];
  float* out = (float*)d_out;

  u16* xb = (u16*)d_ws;                          // frag-tiled x, 8 MB
  u16* wt = (u16*)d_ws + (size_t)M_DIM * K_DIM;  // frag-tiled W[idx], 2 MB

  prep_kernel<<<2048 + 256, 256, 0, stream>>>(x, W, logits, u, xb, wt);
  gemm_kernel<<<512, 256, 0, stream>>>(xb, wt, bvec, logits, u, out);
}